// Round 5
// baseline (299.399 us; speedup 1.0000x reference)
//
#include <hip/hip_runtime.h>

// GatedQueryAttLayer on MI355X (gfx950)
// B=16, S=512, E=1024, H=16, DK=64
// Pipeline: prep (inp->bf16 + W^T cvt) ; fused QKV bf16-MFMA GEMM ;
//           MFMA gating (LDS-staged vectorized apply) ;
//           flash attention (swapped-operand scores, in-register P via shfl).
// Workspace: 70 MB.

typedef __bf16 bf16;
typedef __bf16 bf16x8 __attribute__((ext_vector_type(8)));
typedef __bf16 bf16x4 __attribute__((ext_vector_type(4)));
typedef float  f32x4  __attribute__((ext_vector_type(4)));

#define MFMA16(a,b,c) __builtin_amdgcn_mfma_f32_16x16x32_bf16((a),(b),(c),0,0,0)

#define GLL16(gp, lp)                                                          \
  __builtin_amdgcn_global_load_lds(                                            \
      (__attribute__((address_space(1))) void*)(void*)(gp),                    \
      (__attribute__((address_space(3))) void*)(lp), 16, 0, 0)

static __device__ inline unsigned pk2(float a, float b) {
  unsigned short ua = __builtin_bit_cast(unsigned short, (bf16)a);
  unsigned short ub = __builtin_bit_cast(unsigned short, (bf16)b);
  return (unsigned)ua | ((unsigned)ub << 16);
}

// --------------------------------------------- prep: inp cvt + weight cvt/T
__global__ __launch_bounds__(256) void k_prep(const float* __restrict__ in,
                                              bf16* __restrict__ Xb,
                                              const float* __restrict__ Wq,
                                              const float* __restrict__ Wk,
                                              const float* __restrict__ Wv,
                                              bf16* __restrict__ WT) {
  __shared__ float tile[32][33];
  const int bx = blockIdx.x, t = threadIdx.x;
  if (bx < 8192) {                       // conv: fp32 -> bf16, 4 elems/thread
    int i = bx * 256 + t;
    float4 v = ((const float4*)in)[i];
    bf16x4 o;
    o[0] = (bf16)v.x; o[1] = (bf16)v.y; o[2] = (bf16)v.z; o[3] = (bf16)v.w;
    ((bf16x4*)Xb)[i] = o;
  } else {                               // weight transpose + cvt
    int r = bx - 8192;
    int mat = r >> 10; r &= 1023;
    int kb = r >> 5, nb = r & 31;
    const float* W = (mat == 0) ? Wq : ((mat == 1) ? Wk : Wv);
    bf16* O = WT + (size_t)mat * (1024 * 1024);
    const int tr = t >> 3, tc = (t & 7) * 4;
    float4 v = *(const float4*)&W[(size_t)(kb * 32 + tr) * 1024 + nb * 32 + tc];
    tile[tr][tc] = v.x; tile[tr][tc + 1] = v.y;
    tile[tr][tc + 2] = v.z; tile[tr][tc + 3] = v.w;
    __syncthreads();
    bf16x4 o;
    o[0] = (bf16)tile[tc][tr];     o[1] = (bf16)tile[tc + 1][tr];
    o[2] = (bf16)tile[tc + 2][tr]; o[3] = (bf16)tile[tc + 3][tr];
    *(bf16x4*)&O[(size_t)(nb * 32 + tr) * 1024 + kb * 32 + tc] = o;
  }
}

// -------------------------------------------------- fused QKV projection GEMM
// r3 variant (best measured: 85.7 us): single-buffer, XOR-swizzled staging,
// swapped-operand MFMA (C transposed -> vectorized stores). Plateau for
// K=1024 per rounds 2-4 A/Bs; conflicts 6.29e6 are structural b128 returns.
__global__ __launch_bounds__(256) void k_proj(const bf16* __restrict__ X,
                                              const bf16* __restrict__ WT,
                                              const float* __restrict__ bq,
                                              const float* __restrict__ bk,
                                              const float* __restrict__ bv,
                                              bf16* __restrict__ qw,
                                              bf16* __restrict__ kw,
                                              bf16* __restrict__ vt) {
  __shared__ bf16 As[128 * 32];
  __shared__ bf16 Bs[128 * 32];
  const int tid = threadIdx.x;
  const int m0 = blockIdx.x * 128;
  const int by = blockIdx.y;
  const int mat = by >> 3;             // 0=q,1=k,2=v
  const int n0 = (by & 7) * 128;
  const bf16* Wt = WT + (size_t)mat * (1024 * 1024);
  const float* bias = (mat == 0) ? bq : ((mat == 1) ? bk : bv);
  const int l = tid & 63, w = tid >> 6;
  const int wm = w >> 1, wn = w & 1;
  const int l4 = l & 15, q8 = l >> 4;
  const int rowa = wm * 64 + l4;
  const int rowb = wn * 64 + l4;
  const int ca = q8 ^ ((rowa + (rowa >> 2)) & 3);
  const int cb = q8 ^ ((rowb + (rowb >> 2)) & 3);

  f32x4 acc[4][4] = {};
  for (int kt = 0; kt < 1024; kt += 32) {
    __syncthreads();
#pragma unroll
    for (int i = 0; i < 2; ++i) {
      int chunk = i * 256 + tid;
      int srow = chunk >> 2, cs = chunk & 3;
      int cg = cs ^ ((srow + (srow >> 2)) & 3);
      GLL16(X  + (size_t)(m0 + srow) * 1024 + kt + cg * 8, As + chunk * 8);
      GLL16(Wt + (size_t)(n0 + srow) * 1024 + kt + cg * 8, Bs + chunk * 8);
    }
    __syncthreads();
    bf16x8 a[4], b[4];
#pragma unroll
    for (int i = 0; i < 4; ++i)
      a[i] = *(const bf16x8*)&As[(rowa + i * 16) * 32 + ca * 8];
#pragma unroll
    for (int j = 0; j < 4; ++j)
      b[j] = *(const bf16x8*)&Bs[(rowb + j * 16) * 32 + cb * 8];
#pragma unroll
    for (int i = 0; i < 4; ++i)
#pragma unroll
      for (int j = 0; j < 4; ++j)
        acc[i][j] = MFMA16(b[j], a[i], acc[i][j]);   // swapped: C transposed
  }
#pragma unroll
  for (int i = 0; i < 4; ++i) {
    int m = m0 + wm * 64 + i * 16 + l4;    // 0..8191 = b*512+s
    int b_ = m >> 9, s = m & 511;
#pragma unroll
    for (int j = 0; j < 4; ++j) {
      int nb = n0 + wn * 64 + j * 16 + q8 * 4;   // 4 consecutive n
      if (mat == 2) {
#pragma unroll
        for (int r = 0; r < 4; ++r) {
          int n = nb + r, h = n >> 6, d = n & 63;
          vt[((size_t)(b_ * 16 + h) * 64 + d) * 512 + s] =
              (bf16)(acc[i][j][r] + bias[n]);
        }
      } else {
        float4 bb = *(const float4*)&bias[nb];
        bf16x4 o;
        o[0] = (bf16)(acc[i][j][0] + bb.x);
        o[1] = (bf16)(acc[i][j][1] + bb.y);
        o[2] = (bf16)(acc[i][j][2] + bb.z);
        o[3] = (bf16)(acc[i][j][3] + bb.w);
        bf16* dst = (mat == 0) ? qw : kw;
        *(bf16x4*)&dst[(size_t)m * 1024 + nb] = o;
      }
    }
  }
}

// ----------------------------------------------------------------- gating
// Block = 128 tokens, 4 waves. GEMM1 (fq,fk) + GEMM2 (M) via MFMA; sigmoid(M)
// staged in LDS (Ms aliases dead weight/G buffers) then applied with
// vectorized bf16x8 row RMW (full 128B-line coverage -> no write-amp).
__global__ __launch_bounds__(256, 2) void k_gate(bf16* __restrict__ qw,
                                                 bf16* __restrict__ kw,
                                                 const float* __restrict__ Wfq,
                                                 const float* __restrict__ bfq,
                                                 const float* __restrict__ Wfk,
                                                 const float* __restrict__ bfk,
                                                 const float* __restrict__ Wfg,
                                                 const float* __restrict__ bfg) {
  __shared__ __align__(16) char smraw[56320];
  bf16* sWq = (bf16*)smraw;                 // [64][72]  9216 B
  bf16* sWk = (bf16*)(smraw + 9216);        // [64][72]  9216 B
  bf16* sWg = (bf16*)(smraw + 18432);       // [128][72] 18432 B
  bf16* sG  = (bf16*)(smraw + 36864);       // [128][72] 18432 B
  float* sb = (float*)(smraw + 55296);      // 256 floats... (1024 B)
  bf16* Ms  = (bf16*)smraw;                 // [128][136] 34816 B, aliases after sync
  const int tid = threadIdx.x;

  for (int idx = tid; idx < 4096; idx += 256) {
    int k = idx >> 6, n = idx & 63;
    sWq[n * 72 + k] = (bf16)Wfq[k * 64 + n];
    sWk[n * 72 + k] = (bf16)Wfk[k * 64 + n];
  }
  for (int idx = tid; idx < 8192; idx += 256) {
    int k = idx >> 7, n = idx & 127;
    sWg[n * 72 + k] = (bf16)Wfg[k * 128 + n];
  }
  if (tid < 64) { sb[tid] = bfq[tid]; sb[64 + tid] = bfk[tid]; }
  if (tid < 128) sb[128 + tid] = bfg[tid];
  __syncthreads();

  const int w = tid >> 6, l = tid & 63, l4 = l & 15, q8 = l >> 4;
  const int T0 = blockIdx.x * 128;
  const int rbase = w * 32;

  bf16x8 aq[2][2], ak[2][2];
#pragma unroll
  for (int i = 0; i < 2; ++i)
#pragma unroll
    for (int kk = 0; kk < 2; ++kk) {
      size_t off = (size_t)(T0 + rbase + i * 16 + l4) * 64 + kk * 32 + q8 * 8;
      aq[i][kk] = *(const bf16x8*)&qw[off];
      ak[i][kk] = *(const bf16x8*)&kw[off];
    }

  f32x4 fqc[2][4] = {}, fkc[2][4] = {};
#pragma unroll
  for (int j = 0; j < 4; ++j) {
    bf16x8 bq0 = *(const bf16x8*)&sWq[(j * 16 + l4) * 72 + q8 * 8];
    bf16x8 bq1 = *(const bf16x8*)&sWq[(j * 16 + l4) * 72 + 32 + q8 * 8];
    bf16x8 bk0 = *(const bf16x8*)&sWk[(j * 16 + l4) * 72 + q8 * 8];
    bf16x8 bk1 = *(const bf16x8*)&sWk[(j * 16 + l4) * 72 + 32 + q8 * 8];
#pragma unroll
    for (int i = 0; i < 2; ++i) {
      fqc[i][j] = MFMA16(aq[i][0], bq0, fqc[i][j]);
      fqc[i][j] = MFMA16(aq[i][1], bq1, fqc[i][j]);
      fkc[i][j] = MFMA16(ak[i][0], bk0, fkc[i][j]);
      fkc[i][j] = MFMA16(ak[i][1], bk1, fkc[i][j]);
    }
  }

#pragma unroll
  for (int j = 0; j < 4; ++j) {
    float bqb = sb[j * 16 + l4], bkb = sb[64 + j * 16 + l4];
#pragma unroll
    for (int i = 0; i < 2; ++i)
#pragma unroll
      for (int r = 0; r < 4; ++r) {
        int row = rbase + i * 16 + q8 * 4 + r;
        float g = (fqc[i][j][r] + bqb) * (fkc[i][j][r] + bkb);
        sG[row * 72 + j * 16 + l4] = (bf16)g;
      }
  }
  __syncthreads();

  bf16x8 ag[2][2];
#pragma unroll
  for (int i = 0; i < 2; ++i)
#pragma unroll
    for (int kk = 0; kk < 2; ++kk)
      ag[i][kk] = *(const bf16x8*)&sG[(rbase + i * 16 + l4) * 72 + kk * 32 + q8 * 8];
  f32x4 mc[2][8] = {};
#pragma unroll
  for (int jj = 0; jj < 8; ++jj) {
    bf16x8 bg0 = *(const bf16x8*)&sWg[(jj * 16 + l4) * 72 + q8 * 8];
    bf16x8 bg1 = *(const bf16x8*)&sWg[(jj * 16 + l4) * 72 + 32 + q8 * 8];
#pragma unroll
    for (int i = 0; i < 2; ++i) {
      mc[i][jj] = MFMA16(ag[i][0], bg0, mc[i][jj]);
      mc[i][jj] = MFMA16(ag[i][1], bg1, mc[i][jj]);
    }
  }

  __syncthreads();   // all sG/sWg reads done; Ms may alias them now
#pragma unroll
  for (int jj = 0; jj < 8; ++jj) {
    float bgb = sb[128 + jj * 16 + l4];
#pragma unroll
    for (int i = 0; i < 2; ++i)
#pragma unroll
      for (int r = 0; r < 4; ++r) {
        int row = rbase + i * 16 + q8 * 4 + r;
        float m = mc[i][jj][r] + bgb;
        Ms[row * 136 + jj * 16 + l4] = (bf16)(1.0f / (1.0f + __expf(-m)));
      }
  }
  __syncthreads();

  const float SC = 0.18033688011112042f;  // log2(e)/8 folded into Q
  const int tl = tid >> 1, half = tid & 1;
  bf16* base = (half ? kw : qw) + (size_t)(T0 + tl) * 64;
  const float scl = half ? 1.0f : SC;
#pragma unroll
  for (int c = 0; c < 8; ++c) {
    bf16x8 v = *(const bf16x8*)&base[c * 8];
    bf16x8 m = *(const bf16x8*)&Ms[tl * 136 + half * 64 + c * 8];
    bf16x8 o;
#pragma unroll
    for (int e = 0; e < 8; ++e)
      o[e] = (bf16)((float)v[e] * (float)m[e] * scl);
    *(bf16x8*)&base[c * 8] = o;
  }
}

// ------------------------------------------------------------- attention
// Swapped-operand scores: sc = MFMA16(K_frag, Q_frag) -> lane&15 = q-row
// (matches PV A-operand m-mapping). Softmax stats per row live at lane l4:
// 2-shuffle reductions over q8 lane bits. P enters PV via an in-register
// quad exchange (8 shfl + 4 selects per frag) -- no LDS round trip, no Pb.
__global__ __launch_bounds__(256, 3) void k_attn(const bf16* __restrict__ qw,
                                                 const bf16* __restrict__ kw,
                                                 const bf16* __restrict__ vt,
                                                 float* __restrict__ out) {
  __shared__ bf16 Kt[128 * 72];       // [key][dk] padded
  __shared__ bf16 Vt[64 * 136];       // [dk][key] padded (V^T)
  const int tid = threadIdx.x, w = tid >> 6, l = tid & 63;
  const int l4 = l & 15, q8 = l >> 4;
  const int bx = blockIdx.x, qc = bx & 3, bh = bx >> 2;
  const int b_ = bh >> 4, h = bh & 15;

  // quad-exchange source lanes for P assembly
  const int sA = ((l & 16) << 1) | l4;    // quad 2*(q8&1), same l4
  const int sB = sA + 16;
  const bool ev = (l & 32) == 0;          // q8<2 -> even c-block
  const int sR = (l & 48) | ((l & 48) >> 2);  // q8*16 + q8*4 (add r for bcast)

  bf16x8 qf[2][2];
#pragma unroll
  for (int i = 0; i < 2; ++i)
#pragma unroll
    for (int kk = 0; kk < 2; ++kk) {
      int s = qc * 128 + w * 32 + i * 16 + l4;
      qf[i][kk] = *(const bf16x8*)
          &qw[(((size_t)b_ * 512 + s) * 16 + h) * 64 + kk * 32 + q8 * 8];
    }

  f32x4 o[2][4] = {};
  float mrun[2] = {-3.0e38f, -3.0e38f}, lrun[2] = {0.0f, 0.0f};

  for (int t = 0; t < 4; ++t) {
    __syncthreads();
#pragma unroll
    for (int i = 0; i < 4; ++i) {
      int chunk = i * 256 + tid;
      {  // K tile [key][dk]
        int key = chunk >> 3, c8 = chunk & 7;
        bf16x8 v = *(const bf16x8*)
            &kw[(((size_t)b_ * 512 + t * 128 + key) * 16 + h) * 64 + c8 * 8];
        *(bf16x8*)&Kt[key * 72 + c8 * 8] = v;
      }
      {  // V^T tile [dk][key]
        int d = chunk >> 4, c16 = chunk & 15;
        bf16x8 v = *(const bf16x8*)
            &vt[((size_t)bh * 64 + d) * 512 + t * 128 + c16 * 8];
        *(bf16x8*)&Vt[d * 136 + c16 * 8] = v;
      }
    }
    __syncthreads();

    // scores: lane&15 = q-row (i*16+l4), key = c*16 + q8*4 + r
    f32x4 sc[2][8];
    const f32x4 fz = {};
#pragma unroll
    for (int c = 0; c < 8; ++c) {
      bf16x8 kb0 = *(const bf16x8*)&Kt[(c * 16 + l4) * 72 + q8 * 8];
      bf16x8 kb1 = *(const bf16x8*)&Kt[(c * 16 + l4) * 72 + 32 + q8 * 8];
      sc[0][c] = MFMA16(kb0, qf[0][0], fz);
      sc[0][c] = MFMA16(kb1, qf[0][1], sc[0][c]);
      sc[1][c] = MFMA16(kb0, qf[1][0], fz);
      sc[1][c] = MFMA16(kb1, qf[1][1], sc[1][c]);
    }

    // online softmax (exp2 domain), stats per row at lane l4
#pragma unroll
    for (int i = 0; i < 2; ++i) {
      float mx = sc[i][0][0];
#pragma unroll
      for (int c = 0; c < 8; ++c)
#pragma unroll
        for (int r = 0; r < 4; ++r) mx = fmaxf(mx, sc[i][c][r]);
      mx = fmaxf(mx, __shfl_xor(mx, 16, 64));
      mx = fmaxf(mx, __shfl_xor(mx, 32, 64));
      float mn = fmaxf(mrun[i], mx);
      float al = exp2f(mrun[i] - mn);
      mrun[i] = mn;
      float sm = 0.0f;
#pragma unroll
      for (int c = 0; c < 8; ++c)
#pragma unroll
        for (int r = 0; r < 4; ++r) {
          float p = exp2f(sc[i][c][r] - mn);
          sc[i][c][r] = p;
          sm += p;
        }
      sm += __shfl_xor(sm, 16, 64);
      sm += __shfl_xor(sm, 32, 64);
      lrun[i] = lrun[i] * al + sm;
      // broadcast alpha to the o-layout rows (row = q8*4+r lives at lane l4=row)
#pragma unroll
      for (int r = 0; r < 4; ++r) {
        float ar = __shfl(al, sR + r, 64);
#pragma unroll
        for (int f = 0; f < 4; ++f) o[i][f][r] *= ar;
      }
    }

    // PV: assemble A-layout P frags via quad exchange, then MFMA
#pragma unroll
    for (int kk2 = 0; kk2 < 4; ++kk2) {
      bf16x8 pa[2];
#pragma unroll
      for (int i = 0; i < 2; ++i) {
        unsigned ue0 = pk2(sc[i][2 * kk2][0], sc[i][2 * kk2][1]);
        unsigned ue1 = pk2(sc[i][2 * kk2][2], sc[i][2 * kk2][3]);
        unsigned uo0 = pk2(sc[i][2 * kk2 + 1][0], sc[i][2 * kk2 + 1][1]);
        unsigned uo1 = pk2(sc[i][2 * kk2 + 1][2], sc[i][2 * kk2 + 1][3]);
        unsigned a0 = (unsigned)__shfl((int)ue0, sA, 64);
        unsigned a1 = (unsigned)__shfl((int)ue1, sA, 64);
        unsigned b0 = (unsigned)__shfl((int)uo0, sA, 64);
        unsigned b1 = (unsigned)__shfl((int)uo1, sA, 64);
        unsigned c0 = (unsigned)__shfl((int)ue0, sB, 64);
        unsigned c1 = (unsigned)__shfl((int)ue1, sB, 64);
        unsigned d0 = (unsigned)__shfl((int)uo0, sB, 64);
        unsigned d1 = (unsigned)__shfl((int)uo1, sB, 64);
        union { unsigned u[4]; bf16x8 v; } pu;
        pu.u[0] = ev ? a0 : b0;
        pu.u[1] = ev ? a1 : b1;
        pu.u[2] = ev ? c0 : d0;
        pu.u[3] = ev ? c1 : d1;
        pa[i] = pu.v;
      }
#pragma unroll
      for (int f = 0; f < 4; ++f) {
        bf16x8 vb = *(const bf16x8*)&Vt[(f * 16 + l4) * 136 + kk2 * 32 + q8 * 8];
        o[0][f] = MFMA16(pa[0], vb, o[0][f]);
        o[1][f] = MFMA16(pa[1], vb, o[1][f]);
      }
    }
  }

  // epilogue: normalize (broadcast 1/l to o-layout rows), write [B,S,E] fp32
#pragma unroll
  for (int i = 0; i < 2; ++i)
#pragma unroll
    for (int r = 0; r < 4; ++r) {
      float linv = 1.0f / __shfl(lrun[i], sR + r, 64);
      int srow = qc * 128 + w * 32 + i * 16 + q8 * 4 + r;
#pragma unroll
      for (int f = 0; f < 4; ++f)
        out[(((size_t)b_ * 512 + srow) * 16 + h) * 64 + f * 16 + l4] =
            o[i][f][r] * linv;
    }
}

// ---------------------------------------------------------------- launcher
extern "C" void kernel_launch(void* const* d_in, const int* in_sizes, int n_in,
                              void* d_out, int out_size, void* d_ws,
                              size_t ws_size, hipStream_t stream) {
  (void)in_sizes; (void)n_in; (void)out_size; (void)ws_size;
  const float* inp = (const float*)d_in[0];
  const float* Wq  = (const float*)d_in[1];
  const float* bq  = (const float*)d_in[2];
  const float* Wk  = (const float*)d_in[3];
  const float* bk  = (const float*)d_in[4];
  const float* Wv  = (const float*)d_in[5];
  const float* bv  = (const float*)d_in[6];
  const float* Wfq = (const float*)d_in[7];
  const float* bfq = (const float*)d_in[8];
  const float* Wfk = (const float*)d_in[9];
  const float* bfk = (const float*)d_in[10];
  const float* Wfg = (const float*)d_in[11];
  const float* bfg = (const float*)d_in[12];
  float* out = (float*)d_out;

  char* ws = (char*)d_ws;
  bf16* Xb = (bf16*)(ws);                                // 16 MB
  bf16* WT = (bf16*)(ws + 16777216);                     // 6 MB (3x W^T)
  bf16* qw = (bf16*)(ws + 16777216 + 6291456);           // 16 MB [B,S,H,DK]
  bf16* kw = qw + 8388608;                               // 16 MB
  bf16* vt = kw + 8388608;                               // 16 MB [B,H,DK,S]

  k_prep<<<11264, 256, 0, stream>>>(inp, Xb, Wq, Wk, Wv, WT);
  k_proj<<<dim3(64, 24), 256, 0, stream>>>(Xb, WT, bq, bk, bv, qw, kw, vt);
  k_gate<<<1024, 256, 0, stream>>>(qw, kw, Wfq, bfq, Wfk, bfk, Wfg, bfg);
  k_attn<<<1024, 256, 0, stream>>>(qw, kw, vt, out);
}

// Round 6
// 270.541 us; speedup vs baseline: 1.1067x; 1.1067x over previous
//
#include <hip/hip_runtime.h>

// GatedQueryAttLayer on MI355X (gfx950)
// B=16, S=512, E=1024, H=16, DK=64
// Pipeline: prep (inp->bf16 + W^T cvt) ; fused QKV bf16-MFMA GEMM ;
//           MFMA gating (LDS-staged vectorized apply) ;
//           flash attention (r4 LDS-P structure + XCD-locality swizzle).
// Workspace: 70 MB.

typedef __bf16 bf16;
typedef __bf16 bf16x8 __attribute__((ext_vector_type(8)));
typedef __bf16 bf16x4 __attribute__((ext_vector_type(4)));
typedef float  f32x4  __attribute__((ext_vector_type(4)));

#define MFMA16(a,b,c) __builtin_amdgcn_mfma_f32_16x16x32_bf16((a),(b),(c),0,0,0)

#define GLL16(gp, lp)                                                          \
  __builtin_amdgcn_global_load_lds(                                            \
      (__attribute__((address_space(1))) void*)(void*)(gp),                    \
      (__attribute__((address_space(3))) void*)(lp), 16, 0, 0)

// --------------------------------------------- prep: inp cvt + weight cvt/T
__global__ __launch_bounds__(256) void k_prep(const float* __restrict__ in,
                                              bf16* __restrict__ Xb,
                                              const float* __restrict__ Wq,
                                              const float* __restrict__ Wk,
                                              const float* __restrict__ Wv,
                                              bf16* __restrict__ WT) {
  __shared__ float tile[32][33];
  const int bx = blockIdx.x, t = threadIdx.x;
  if (bx < 8192) {                       // conv: fp32 -> bf16, 4 elems/thread
    int i = bx * 256 + t;
    float4 v = ((const float4*)in)[i];
    bf16x4 o;
    o[0] = (bf16)v.x; o[1] = (bf16)v.y; o[2] = (bf16)v.z; o[3] = (bf16)v.w;
    ((bf16x4*)Xb)[i] = o;
  } else {                               // weight transpose + cvt
    int r = bx - 8192;
    int mat = r >> 10; r &= 1023;
    int kb = r >> 5, nb = r & 31;
    const float* W = (mat == 0) ? Wq : ((mat == 1) ? Wk : Wv);
    bf16* O = WT + (size_t)mat * (1024 * 1024);
    const int tr = t >> 3, tc = (t & 7) * 4;
    float4 v = *(const float4*)&W[(size_t)(kb * 32 + tr) * 1024 + nb * 32 + tc];
    tile[tr][tc] = v.x; tile[tr][tc + 1] = v.y;
    tile[tr][tc + 2] = v.z; tile[tr][tc + 3] = v.w;
    __syncthreads();
    bf16x4 o;
    o[0] = (bf16)tile[tc][tr];     o[1] = (bf16)tile[tc + 1][tr];
    o[2] = (bf16)tile[tc + 2][tr]; o[3] = (bf16)tile[tc + 3][tr];
    *(bf16x4*)&O[(size_t)(nb * 32 + tr) * 1024 + kb * 32 + tc] = o;
  }
}

// -------------------------------------------------- fused QKV projection GEMM
// r3 variant (best measured: 85.7 us): single-buffer, XOR-swizzled staging,
// swapped-operand MFMA (C transposed -> vectorized stores). Plateau for
// K=1024 per rounds 2-4 A/Bs; conflicts 6.29e6 are structural b128 returns.
__global__ __launch_bounds__(256) void k_proj(const bf16* __restrict__ X,
                                              const bf16* __restrict__ WT,
                                              const float* __restrict__ bq,
                                              const float* __restrict__ bk,
                                              const float* __restrict__ bv,
                                              bf16* __restrict__ qw,
                                              bf16* __restrict__ kw,
                                              bf16* __restrict__ vt) {
  __shared__ bf16 As[128 * 32];
  __shared__ bf16 Bs[128 * 32];
  const int tid = threadIdx.x;
  const int m0 = blockIdx.x * 128;
  const int by = blockIdx.y;
  const int mat = by >> 3;             // 0=q,1=k,2=v
  const int n0 = (by & 7) * 128;
  const bf16* Wt = WT + (size_t)mat * (1024 * 1024);
  const float* bias = (mat == 0) ? bq : ((mat == 1) ? bk : bv);
  const int l = tid & 63, w = tid >> 6;
  const int wm = w >> 1, wn = w & 1;
  const int l4 = l & 15, q8 = l >> 4;
  const int rowa = wm * 64 + l4;
  const int rowb = wn * 64 + l4;
  const int ca = q8 ^ ((rowa + (rowa >> 2)) & 3);
  const int cb = q8 ^ ((rowb + (rowb >> 2)) & 3);

  f32x4 acc[4][4] = {};
  for (int kt = 0; kt < 1024; kt += 32) {
    __syncthreads();
#pragma unroll
    for (int i = 0; i < 2; ++i) {
      int chunk = i * 256 + tid;
      int srow = chunk >> 2, cs = chunk & 3;
      int cg = cs ^ ((srow + (srow >> 2)) & 3);
      GLL16(X  + (size_t)(m0 + srow) * 1024 + kt + cg * 8, As + chunk * 8);
      GLL16(Wt + (size_t)(n0 + srow) * 1024 + kt + cg * 8, Bs + chunk * 8);
    }
    __syncthreads();
    bf16x8 a[4], b[4];
#pragma unroll
    for (int i = 0; i < 4; ++i)
      a[i] = *(const bf16x8*)&As[(rowa + i * 16) * 32 + ca * 8];
#pragma unroll
    for (int j = 0; j < 4; ++j)
      b[j] = *(const bf16x8*)&Bs[(rowb + j * 16) * 32 + cb * 8];
#pragma unroll
    for (int i = 0; i < 4; ++i)
#pragma unroll
      for (int j = 0; j < 4; ++j)
        acc[i][j] = MFMA16(b[j], a[i], acc[i][j]);   // swapped: C transposed
  }
#pragma unroll
  for (int i = 0; i < 4; ++i) {
    int m = m0 + wm * 64 + i * 16 + l4;    // 0..8191 = b*512+s
    int b_ = m >> 9, s = m & 511;
#pragma unroll
    for (int j = 0; j < 4; ++j) {
      int nb = n0 + wn * 64 + j * 16 + q8 * 4;   // 4 consecutive n
      if (mat == 2) {
#pragma unroll
        for (int r = 0; r < 4; ++r) {
          int n = nb + r, h = n >> 6, d = n & 63;
          vt[((size_t)(b_ * 16 + h) * 64 + d) * 512 + s] =
              (bf16)(acc[i][j][r] + bias[n]);
        }
      } else {
        float4 bb = *(const float4*)&bias[nb];
        bf16x4 o;
        o[0] = (bf16)(acc[i][j][0] + bb.x);
        o[1] = (bf16)(acc[i][j][1] + bb.y);
        o[2] = (bf16)(acc[i][j][2] + bb.z);
        o[3] = (bf16)(acc[i][j][3] + bb.w);
        bf16* dst = (mat == 0) ? qw : kw;
        *(bf16x4*)&dst[(size_t)m * 1024 + nb] = o;
      }
    }
  }
}

// ----------------------------------------------------------------- gating
// Block = 128 tokens, 4 waves. GEMM1 (fq,fk) + GEMM2 (M) via MFMA; sigmoid(M)
// staged in LDS (Ms aliases dead weight/G buffers) then applied with
// vectorized bf16x8 row RMW (full 128B-line coverage -> no write-amp).
__global__ __launch_bounds__(256, 2) void k_gate(bf16* __restrict__ qw,
                                                 bf16* __restrict__ kw,
                                                 const float* __restrict__ Wfq,
                                                 const float* __restrict__ bfq,
                                                 const float* __restrict__ Wfk,
                                                 const float* __restrict__ bfk,
                                                 const float* __restrict__ Wfg,
                                                 const float* __restrict__ bfg) {
  __shared__ __align__(16) char smraw[56320];
  bf16* sWq = (bf16*)smraw;                 // [64][72]  9216 B
  bf16* sWk = (bf16*)(smraw + 9216);        // [64][72]  9216 B
  bf16* sWg = (bf16*)(smraw + 18432);       // [128][72] 18432 B
  bf16* sG  = (bf16*)(smraw + 36864);       // [128][72] 18432 B
  float* sb = (float*)(smraw + 55296);      // 256 floats (1024 B)
  bf16* Ms  = (bf16*)smraw;                 // [128][136] 34816 B, aliases after sync
  const int tid = threadIdx.x;

  for (int idx = tid; idx < 4096; idx += 256) {
    int k = idx >> 6, n = idx & 63;
    sWq[n * 72 + k] = (bf16)Wfq[k * 64 + n];
    sWk[n * 72 + k] = (bf16)Wfk[k * 64 + n];
  }
  for (int idx = tid; idx < 8192; idx += 256) {
    int k = idx >> 7, n = idx & 127;
    sWg[n * 72 + k] = (bf16)Wfg[k * 128 + n];
  }
  if (tid < 64) { sb[tid] = bfq[tid]; sb[64 + tid] = bfk[tid]; }
  if (tid < 128) sb[128 + tid] = bfg[tid];
  __syncthreads();

  const int w = tid >> 6, l = tid & 63, l4 = l & 15, q8 = l >> 4;
  const int T0 = blockIdx.x * 128;
  const int rbase = w * 32;

  bf16x8 aq[2][2], ak[2][2];
#pragma unroll
  for (int i = 0; i < 2; ++i)
#pragma unroll
    for (int kk = 0; kk < 2; ++kk) {
      size_t off = (size_t)(T0 + rbase + i * 16 + l4) * 64 + kk * 32 + q8 * 8;
      aq[i][kk] = *(const bf16x8*)&qw[off];
      ak[i][kk] = *(const bf16x8*)&kw[off];
    }

  f32x4 fqc[2][4] = {}, fkc[2][4] = {};
#pragma unroll
  for (int j = 0; j < 4; ++j) {
    bf16x8 bq0 = *(const bf16x8*)&sWq[(j * 16 + l4) * 72 + q8 * 8];
    bf16x8 bq1 = *(const bf16x8*)&sWq[(j * 16 + l4) * 72 + 32 + q8 * 8];
    bf16x8 bk0 = *(const bf16x8*)&sWk[(j * 16 + l4) * 72 + q8 * 8];
    bf16x8 bk1 = *(const bf16x8*)&sWk[(j * 16 + l4) * 72 + 32 + q8 * 8];
#pragma unroll
    for (int i = 0; i < 2; ++i) {
      fqc[i][j] = MFMA16(aq[i][0], bq0, fqc[i][j]);
      fqc[i][j] = MFMA16(aq[i][1], bq1, fqc[i][j]);
      fkc[i][j] = MFMA16(ak[i][0], bk0, fkc[i][j]);
      fkc[i][j] = MFMA16(ak[i][1], bk1, fkc[i][j]);
    }
  }

#pragma unroll
  for (int j = 0; j < 4; ++j) {
    float bqb = sb[j * 16 + l4], bkb = sb[64 + j * 16 + l4];
#pragma unroll
    for (int i = 0; i < 2; ++i)
#pragma unroll
      for (int r = 0; r < 4; ++r) {
        int row = rbase + i * 16 + q8 * 4 + r;
        float g = (fqc[i][j][r] + bqb) * (fkc[i][j][r] + bkb);
        sG[row * 72 + j * 16 + l4] = (bf16)g;
      }
  }
  __syncthreads();

  bf16x8 ag[2][2];
#pragma unroll
  for (int i = 0; i < 2; ++i)
#pragma unroll
    for (int kk = 0; kk < 2; ++kk)
      ag[i][kk] = *(const bf16x8*)&sG[(rbase + i * 16 + l4) * 72 + kk * 32 + q8 * 8];
  f32x4 mc[2][8] = {};
#pragma unroll
  for (int jj = 0; jj < 8; ++jj) {
    bf16x8 bg0 = *(const bf16x8*)&sWg[(jj * 16 + l4) * 72 + q8 * 8];
    bf16x8 bg1 = *(const bf16x8*)&sWg[(jj * 16 + l4) * 72 + 32 + q8 * 8];
#pragma unroll
    for (int i = 0; i < 2; ++i) {
      mc[i][jj] = MFMA16(ag[i][0], bg0, mc[i][jj]);
      mc[i][jj] = MFMA16(ag[i][1], bg1, mc[i][jj]);
    }
  }

  __syncthreads();   // all sG/sWg reads done; Ms may alias them now
#pragma unroll
  for (int jj = 0; jj < 8; ++jj) {
    float bgb = sb[128 + jj * 16 + l4];
#pragma unroll
    for (int i = 0; i < 2; ++i)
#pragma unroll
      for (int r = 0; r < 4; ++r) {
        int row = rbase + i * 16 + q8 * 4 + r;
        float m = mc[i][jj][r] + bgb;
        Ms[row * 136 + jj * 16 + l4] = (bf16)(1.0f / (1.0f + __expf(-m)));
      }
  }
  __syncthreads();

  const float SC = 0.18033688011112042f;  // log2(e)/8 folded into Q
  const int tl = tid >> 1, half = tid & 1;
  bf16* base = (half ? kw : qw) + (size_t)(T0 + tl) * 64;
  const float scl = half ? 1.0f : SC;
#pragma unroll
  for (int c = 0; c < 8; ++c) {
    bf16x8 v = *(const bf16x8*)&base[c * 8];
    bf16x8 m = *(const bf16x8*)&Ms[tl * 136 + half * 64 + c * 8];
    bf16x8 o;
#pragma unroll
    for (int e = 0; e < 8; ++e)
      o[e] = (bf16)((float)v[e] * (float)m[e] * scl);
    *(bf16x8*)&base[c * 8] = o;
  }
}

// ------------------------------------------------------------- attention
// r4 structure (best measured): LDS P round-trip, per-row softmax stats.
// XCD-LOCALITY SWIZZLE: the 4 q-chunk blocks of one (b,h) share bx%8 ->
// same XCD (round-robin dispatch) -> K/V refetch hits that XCD's L2
// (working set 32 bh x 128 KB = 4 MB = one L2).
__global__ __launch_bounds__(256, 2) void k_attn(const bf16* __restrict__ qw,
                                                 const bf16* __restrict__ kw,
                                                 const bf16* __restrict__ vt,
                                                 float* __restrict__ out) {
  __shared__ bf16 Kt[128 * 72];       // [key][dk] padded
  __shared__ bf16 Vt[64 * 136];       // [dk][key] padded (V^T)
  __shared__ bf16 Pb[4][32 * 40];     // per-wave P chunk [32 rows][32 keys] padded
  const int tid = threadIdx.x, w = tid >> 6, l = tid & 63;
  const int l4 = l & 15, q8 = l >> 4;
  const int bx = blockIdx.x;
  const int slot = bx >> 3;
  const int qc = slot & 3;
  const int bh = (bx & 7) + 8 * (slot >> 2);
  const int b_ = bh >> 4, h = bh & 15;
  bf16* Pw = &Pb[w][0];

  bf16x8 qf[2][2];
#pragma unroll
  for (int i = 0; i < 2; ++i)
#pragma unroll
    for (int kk = 0; kk < 2; ++kk) {
      int s = qc * 128 + w * 32 + i * 16 + l4;
      qf[i][kk] = *(const bf16x8*)
          &qw[(((size_t)b_ * 512 + s) * 16 + h) * 64 + kk * 32 + q8 * 8];
    }

  f32x4 o[2][4] = {};
  float mrun[2][4], lrun[2][4];
#pragma unroll
  for (int i = 0; i < 2; ++i)
#pragma unroll
    for (int r = 0; r < 4; ++r) { mrun[i][r] = -3.0e38f; lrun[i][r] = 0.0f; }

  for (int t = 0; t < 4; ++t) {
    __syncthreads();
#pragma unroll
    for (int i = 0; i < 4; ++i) {
      int chunk = i * 256 + tid;
      {  // K tile: straight copy, [key][dk]
        int key = chunk >> 3, c8 = chunk & 7;
        bf16x8 v = *(const bf16x8*)
            &kw[(((size_t)b_ * 512 + t * 128 + key) * 16 + h) * 64 + c8 * 8];
        *(bf16x8*)&Kt[key * 72 + c8 * 8] = v;
      }
      {  // V^T tile: straight copy from global V^T, [dk][key]
        int d = chunk >> 4, c16 = chunk & 15;
        bf16x8 v = *(const bf16x8*)
            &vt[((size_t)bh * 64 + d) * 512 + t * 128 + c16 * 8];
        *(bf16x8*)&Vt[d * 136 + c16 * 8] = v;
      }
    }
    __syncthreads();

    // scores: D[q (2x16)][key (8x16)]
    f32x4 sc[2][8];
    const f32x4 fz = {};
#pragma unroll
    for (int c = 0; c < 8; ++c) {
      bf16x8 kb0 = *(const bf16x8*)&Kt[(c * 16 + l4) * 72 + q8 * 8];
      sc[0][c] = MFMA16(qf[0][0], kb0, fz);
      sc[1][c] = MFMA16(qf[1][0], kb0, fz);
      bf16x8 kb1 = *(const bf16x8*)&Kt[(c * 16 + l4) * 72 + 32 + q8 * 8];
      sc[0][c] = MFMA16(qf[0][1], kb1, sc[0][c]);
      sc[1][c] = MFMA16(qf[1][1], kb1, sc[1][c]);
    }

    // online softmax (exp2 domain); row stats shared by 16-lane groups
#pragma unroll
    for (int i = 0; i < 2; ++i) {
      float al[4];
#pragma unroll
      for (int r = 0; r < 4; ++r) {
        float mx = sc[i][0][r];
#pragma unroll
        for (int c = 1; c < 8; ++c) mx = fmaxf(mx, sc[i][c][r]);
        mx = fmaxf(mx, __shfl_xor(mx, 1));
        mx = fmaxf(mx, __shfl_xor(mx, 2));
        mx = fmaxf(mx, __shfl_xor(mx, 4));
        mx = fmaxf(mx, __shfl_xor(mx, 8));
        float mn = fmaxf(mrun[i][r], mx);
        al[r] = exp2f(mrun[i][r] - mn);
        mrun[i][r] = mn;
        float sm = 0.0f;
#pragma unroll
        for (int c = 0; c < 8; ++c) {
          float p = exp2f(sc[i][c][r] - mn);
          sc[i][c][r] = p;
          sm += p;
        }
        sm += __shfl_xor(sm, 1); sm += __shfl_xor(sm, 2);
        sm += __shfl_xor(sm, 4); sm += __shfl_xor(sm, 8);
        lrun[i][r] = lrun[i][r] * al[r] + sm;
      }
#pragma unroll
      for (int f = 0; f < 4; ++f)
#pragma unroll
        for (int r = 0; r < 4; ++r) o[i][f][r] *= al[r];
    }

    // PV: C/D-layout P -> LDS (32-key chunks) -> A-layout frags -> MFMA
#pragma unroll
    for (int kk2 = 0; kk2 < 4; ++kk2) {
#pragma unroll
      for (int i = 0; i < 2; ++i)
#pragma unroll
        for (int cc = 0; cc < 2; ++cc) {
          int c = kk2 * 2 + cc;
#pragma unroll
          for (int r = 0; r < 4; ++r)
            Pw[(i * 16 + q8 * 4 + r) * 40 + cc * 16 + l4] = (bf16)sc[i][c][r];
        }
      bf16x8 pa0 = *(const bf16x8*)&Pw[(l4) * 40 + q8 * 8];
      bf16x8 pa1 = *(const bf16x8*)&Pw[(16 + l4) * 40 + q8 * 8];
#pragma unroll
      for (int f = 0; f < 4; ++f) {
        bf16x8 vb = *(const bf16x8*)&Vt[(f * 16 + l4) * 136 + kk2 * 32 + q8 * 8];
        o[0][f] = MFMA16(pa0, vb, o[0][f]);
        o[1][f] = MFMA16(pa1, vb, o[1][f]);
      }
    }
  }

  // epilogue: normalize, write [B,S,E] fp32
#pragma unroll
  for (int i = 0; i < 2; ++i)
#pragma unroll
    for (int r = 0; r < 4; ++r) {
      int srow = qc * 128 + w * 32 + i * 16 + q8 * 4 + r;
      float inv = 1.0f / lrun[i][r];
#pragma unroll
      for (int f = 0; f < 4; ++f)
        out[(((size_t)b_ * 512 + srow) * 16 + h) * 64 + f * 16 + l4] =
            o[i][f][r] * inv;
    }
}

// ---------------------------------------------------------------- launcher
extern "C" void kernel_launch(void* const* d_in, const int* in_sizes, int n_in,
                              void* d_out, int out_size, void* d_ws,
                              size_t ws_size, hipStream_t stream) {
  (void)in_sizes; (void)n_in; (void)out_size; (void)ws_size;
  const float* inp = (const float*)d_in[0];
  const float* Wq  = (const float*)d_in[1];
  const float* bq  = (const float*)d_in[2];
  const float* Wk  = (const float*)d_in[3];
  const float* bk  = (const float*)d_in[4];
  const float* Wv  = (const float*)d_in[5];
  const float* bv  = (const float*)d_in[6];
  const float* Wfq = (const float*)d_in[7];
  const float* bfq = (const float*)d_in[8];
  const float* Wfk = (const float*)d_in[9];
  const float* bfk = (const float*)d_in[10];
  const float* Wfg = (const float*)d_in[11];
  const float* bfg = (const float*)d_in[12];
  float* out = (float*)d_out;

  char* ws = (char*)d_ws;
  bf16* Xb = (bf16*)(ws);                                // 16 MB
  bf16* WT = (bf16*)(ws + 16777216);                     // 6 MB (3x W^T)
  bf16* qw = (bf16*)(ws + 16777216 + 6291456);           // 16 MB [B,S,H,DK]
  bf16* kw = qw + 8388608;                               // 16 MB
  bf16* vt = kw + 8388608;                               // 16 MB [B,H,DK,S]

  k_prep<<<11264, 256, 0, stream>>>(inp, Xb, Wq, Wk, Wv, WT);
  k_proj<<<dim3(64, 24), 256, 0, stream>>>(Xb, WT, bq, bk, bv, qw, kw, vt);
  k_gate<<<1024, 256, 0, stream>>>(qw, kw, Wfq, bfq, Wfk, bfk, Wfg, bfg);
  k_attn<<<1024, 256, 0, stream>>>(qw, kw, vt, out);
}